// Round 11
// baseline (152.089 us; speedup 1.0000x reference)
//
#include <hip/hip_runtime.h>
#include <hip/hip_bf16.h>
#include <math.h>

typedef __hip_bfloat16 bf16;
typedef __attribute__((ext_vector_type(4))) float f32x4;
typedef __attribute__((ext_vector_type(8))) short short8;

#define HIDN 768
#define NTOK 2048   // B*S
#define NH 12
#define HD 64
#define ISZ 3072
#define SEQ 512

__device__ __forceinline__ bf16 f2bf(float x){ return __float2bfloat16(x); }
// tanh-approx gelu, exp2 form (log2e folded into poly; exp2f = raw v_exp_f32)
__device__ __forceinline__ float gelu_fast(float x){
    float u = x * fmaf(x*x, -0.1029432f, -2.302208f);   // -2*log2e*(c0 + c1 x^2)*x
    float e = exp2f(u);
    return x * __builtin_amdgcn_rcpf(1.0f + e);
}

// async global->LDS, 16B per lane (LDS dest = wave base + lane*16)
__device__ __forceinline__ void gload16(const bf16* g, bf16* l){
    __builtin_amdgcn_global_load_lds(
        (const __attribute__((address_space(1))) unsigned int*)g,
        (__attribute__((address_space(3))) unsigned int*)l,
        16, 0, 0);
}

#define FENCE asm volatile("" ::: "memory")

// ---------------------------------------------------------------------------
// Unified pipelined GEMM, K=768 fixed: C = A[M,768] @ B[N,768]^T.
// 512 thr = 8 waves (4M x 2N); tile 128x64; BK=64, NT=12 fully unrolled;
// 3 LDS buffers, prefetch depth 2, counted vmcnt(6) steady state;
// XOR-swizzled LDS via pre-swizzled global source; setprio on MFMA.
// Ledger: buf (kt+2)%3 written at iter kt was last ds_read at iter kt-1,
// whose reads completed before iter kt-1's closing barrier.
// EPI: 0 = bias[col] add, bf16        (QKV)
//      1 = plain f32 store            (FFN2 split-K partials, z-batched)
//      2 = v*bias[col>>6], bf16       (WcT with w_kp folded)
// ---------------------------------------------------------------------------
template<int EPI>
__global__ __launch_bounds__(512)
void gemm_pipe(const bf16* __restrict__ A, const bf16* __restrict__ B,
               void* __restrict__ Cbase, const float* __restrict__ bias,
               int lda, int ldb, int ldc,
               long sAz, long sBz, long sCz)
{
    __shared__ __align__(16) char hlds[3*24576];
    int z = blockIdx.z;
    A += (long)z*sAz; B += (long)z*sBz;

    int nwg  = gridDim.x * gridDim.y;
    int orig = blockIdx.y * gridDim.x + blockIdx.x;
    int q8 = nwg >> 3, r8 = nwg & 7;
    int xcd = orig & 7, idx = orig >> 3;
    int wg = (xcd < r8 ? xcd*(q8+1) : r8*(q8+1) + (xcd-r8)*q8) + idx;
    int bn = wg % gridDim.x, bm = wg / gridDim.x;

    int t = threadIdx.x;
    int wave = t >> 6, lane = t & 63;
    int wm = (wave >> 1) << 5;    // 0,32,64,96
    int wn = (wave & 1) << 5;     // 0,32
    int lr = lane & 15, lg = lane >> 4;
    int x7 = lr & 7;
    int gb0 = ((lg    ) ^ x7) << 4;
    int gb1 = ((4 | lg) ^ x7) << 4;

    int srow = t >> 3;
    int glog = (t & 7) ^ (srow & 7);
    const bf16* Ag0 = A + (long)(bm*128 + srow)*lda + glog*8;
    const bf16* Ag1 = Ag0 + (long)64*lda;
    const bf16* Bg0 = B + (long)(bn*64 + srow)*ldb + glog*8;

#define PSTAGE(buf,kt) { \
    gload16(Ag0 + (kt)*64, (bf16*)(hlds + (buf)*24576 + t*16)); \
    gload16(Ag1 + (kt)*64, (bf16*)(hlds + (buf)*24576 + 8192 + t*16)); \
    gload16(Bg0 + (kt)*64, (bf16*)(hlds + (buf)*24576 + 16384 + t*16)); }

    PSTAGE(0, 0);
    PSTAGE(1, 1);

    f32x4 acc[2][2] = {};

    #pragma unroll
    for (int kt = 0; kt < 12; ++kt){
        if (kt <= 9) PSTAGE((kt+2)%3, kt+2);
        if (kt <= 9)      asm volatile("s_waitcnt vmcnt(6)" ::: "memory");
        else if (kt == 10) asm volatile("s_waitcnt vmcnt(3)" ::: "memory");
        else               asm volatile("s_waitcnt vmcnt(0)" ::: "memory");
        FENCE; __builtin_amdgcn_s_barrier(); FENCE;

        const char* Lb = hlds + (kt%3)*24576;
        short8 af[2][2], bfr[2][2];
        #pragma unroll
        for (int m=0;m<2;m++){
            const char* pr = Lb + (wm + m*16 + lr)*128;
            af[m][0] = *(const short8*)(pr + gb0);
            af[m][1] = *(const short8*)(pr + gb1);
        }
        #pragma unroll
        for (int n=0;n<2;n++){
            const char* pr = Lb + 16384 + (wn + n*16 + lr)*128;
            bfr[n][0] = *(const short8*)(pr + gb0);
            bfr[n][1] = *(const short8*)(pr + gb1);
        }
        __builtin_amdgcn_s_setprio(1);
        #pragma unroll
        for (int m=0;m<2;m++)
            #pragma unroll
            for (int n=0;n<2;n++)
                #pragma unroll
                for (int kk=0;kk<2;kk++)
                    acc[m][n] = __builtin_amdgcn_mfma_f32_16x16x32_bf16(af[m][kk], bfr[n][kk], acc[m][n], 0,0,0);
        __builtin_amdgcn_s_setprio(0);
        FENCE; __builtin_amdgcn_s_barrier(); FENCE;
    }
#undef PSTAGE

    #pragma unroll
    for (int m=0;m<2;m++){
        #pragma unroll
        for (int n=0;n<2;n++){
            int col = bn*64 + wn + n*16 + lr;
            float bcol = (EPI==0) ? bias[col] : 0.f;
            #pragma unroll
            for (int i=0;i<4;i++){
                long row = (long)bm*128 + wm + m*16 + lg*4 + i;
                float v = acc[m][n][i];
                if constexpr (EPI==0){
                    ((bf16*)Cbase)[row*ldc+col] = f2bf(v + bcol);
                } else if constexpr (EPI==1){
                    ((float*)Cbase + (long)z*sCz)[row*ldc+col] = v;
                } else {
                    ((bf16*)Cbase)[row*ldc+col] = f2bf(v * bias[col>>6]);
                }
            }
        }
    }
}

// ---------------------------------------------------------------------------
// bhc GEMM (m97 structure, 24 blocks is fine for 0.6 GFLOP):
// bhc[h][c] = w_kp[h]*(bo_pad @ WiT^T)[h][c] + bi[c], row<12 guard
// ---------------------------------------------------------------------------
__global__ __launch_bounds__(256)
void gemm_bhc(const bf16* __restrict__ A, const bf16* __restrict__ B,
              float* __restrict__ C, const float* __restrict__ bias,
              const float* __restrict__ scales)
{
    __shared__ bf16 As[128*32];
    __shared__ bf16 Bs[128*32];

    int bn = blockIdx.x, bm = 0;
    int t = threadIdx.x;
    int wave = t >> 6, lane = t & 63;
    int wm = (wave >> 1) << 6;
    int wn = (wave & 1) << 6;
    int lr = lane & 15, lg = lane >> 4;

    f32x4 acc[4][4] = {};

    int arow = t >> 2;
    int acol = (t & 3) << 3;
    const bf16* Ag0 = A + (long)(bm*128 + arow)*HIDN + acol;
    const bf16* Ag1 = Ag0 + (long)64*HIDN;
    const bf16* Bg0 = B + (long)(bn*128 + arow)*HIDN + acol;
    const bf16* Bg1 = Bg0 + (long)64*HIDN;
    bf16* Al = As + t*8;
    bf16* Bl = Bs + t*8;

    for (int k0 = 0; k0 < HIDN; k0 += 32) {
        __syncthreads();
        gload16(Ag0, Al);
        gload16(Ag1, Al + 64*32);
        gload16(Bg0, Bl);
        gload16(Bg1, Bl + 64*32);
        Ag0 += 32; Ag1 += 32; Bg0 += 32; Bg1 += 32;
        __syncthreads();
        short8 af[4], bfr[4];
        #pragma unroll
        for (int m=0;m<4;m++) af[m]  = *(short8*)&As[(wm + m*16 + lr)*32 + lg*8];
        #pragma unroll
        for (int n=0;n<4;n++) bfr[n] = *(short8*)&Bs[(wn + n*16 + lr)*32 + lg*8];
        #pragma unroll
        for (int m=0;m<4;m++)
            #pragma unroll
            for (int n=0;n<4;n++)
                acc[m][n] = __builtin_amdgcn_mfma_f32_16x16x32_bf16(af[m], bfr[n], acc[m][n], 0,0,0);
    }

    #pragma unroll
    for (int m=0;m<4;m++){
        #pragma unroll
        for (int n=0;n<4;n++){
            int col = bn*128 + wn + n*16 + lr;
            float bcol = bias[col];
            #pragma unroll
            for (int i=0;i<4;i++){
                int row = wm + m*16 + lg*4 + i;
                if (row < NH) C[row*ISZ+col] = fmaf(scales[row], acc[m][n][i], bcol);
            }
        }
    }
}

// ---------------------------------------------------------------------------
// Fused flash attention (max-free single pass; scores provably small).
// 128 threads = 2 waves; wave owns 16 q-rows. Zero barriers (per-wave LDS).
// ---------------------------------------------------------------------------
__global__ __launch_bounds__(128)
void flash_attn(const bf16* __restrict__ qkv, const bf16* __restrict__ Vt,
                const float* __restrict__ mask, bf16* __restrict__ ctx2)
{
    __shared__ __align__(16) char p_lds[4096];   // 2 waves x [16 q][64 k] bf16
    int z = blockIdx.y;
    int b = z / NH, h = z - b*NH;
    int t = threadIdx.x;
    int wave = t >> 6, lane = t & 63;
    int q0 = blockIdx.x*32 + wave*16;
    int lr = lane & 15, lg = lane >> 4;
    int x7 = lr & 7;
    int gb0 = ((lg    ) ^ x7) << 4;
    int gb1 = ((4 | lg) ^ x7) << 4;

    const bf16* Qp = qkv + (long)(b*SEQ + q0 + lr)*(3*HIDN) + h*HD + lg*8;
    short8 aq0 = *(const short8*)(Qp);
    short8 aq1 = *(const short8*)(Qp + 32);

    const bf16* Kb = qkv + (long)b*SEQ*(3*HIDN) + HIDN + h*HD + lg*8;
    const bf16* Vb = Vt + (long)z*HD*SEQ;
    const float* mb = mask + b*SEQ;
    char* pw = p_lds + wave*2048;

    f32x4 o[4] = {};
    float lsum[4] = {0.f,0.f,0.f,0.f};

    for (int kt = 0; kt < 8; ++kt){
        int kbase = kt*64;
        short8 bk0[4], bk1[4];
        #pragma unroll
        for (int nf=0;nf<4;nf++){
            const bf16* kp = Kb + (long)(kbase + nf*16 + lr)*(3*HIDN);
            bk0[nf] = *(const short8*)(kp);
            bk1[nf] = *(const short8*)(kp + 32);
        }
        f32x4 s[4] = {};
        #pragma unroll
        for (int nf=0;nf<4;nf++){
            s[nf] = __builtin_amdgcn_mfma_f32_16x16x32_bf16(aq0, bk0[nf], s[nf], 0,0,0);
            s[nf] = __builtin_amdgcn_mfma_f32_16x16x32_bf16(aq1, bk1[nf], s[nf], 0,0,0);
        }
        short8 bv0[4], bv1[4];
        #pragma unroll
        for (int nf=0;nf<4;nf++){
            const bf16* vp = Vb + (long)(nf*16 + lr)*SEQ + kbase + lg*8;
            bv0[nf] = *(const short8*)(vp);
            bv1[nf] = *(const short8*)(vp + 32);
        }
        #pragma unroll
        for (int nf=0;nf<4;nf++){
            float mkl = mb[kbase + nf*16 + lr] * 1.442695041f;
            int gk = nf*2 + (lr>>3);
            #pragma unroll
            for (int i=0;i<4;i++){
                int q = lg*4 + i;
                float e = exp2f(fmaf(s[nf][i], 0.18033688f, mkl));
                lsum[i] += e;
                *(bf16*)(pw + q*128 + ((gk ^ (q&7))<<4) + (lr&7)*2) = f2bf(e);
            }
        }
        short8 ap0 = *(const short8*)(pw + lr*128 + gb0);
        short8 ap1 = *(const short8*)(pw + lr*128 + gb1);
        #pragma unroll
        for (int nf=0;nf<4;nf++){
            o[nf] = __builtin_amdgcn_mfma_f32_16x16x32_bf16(ap0, bv0[nf], o[nf], 0,0,0);
            o[nf] = __builtin_amdgcn_mfma_f32_16x16x32_bf16(ap1, bv1[nf], o[nf], 0,0,0);
        }
    }
    #pragma unroll
    for (int i=0;i<4;i++){
        float v = lsum[i];
        v += __shfl_xor(v, 1, 64);
        v += __shfl_xor(v, 2, 64);
        v += __shfl_xor(v, 4, 64);
        v += __shfl_xor(v, 8, 64);
        lsum[i] = __builtin_amdgcn_rcpf(v);
    }
    bf16* Cp = ctx2 + (long)(b*SEQ + q0)*HIDN + h*HD;
    #pragma unroll
    for (int nf=0;nf<4;nf++)
        #pragma unroll
        for (int i=0;i<4;i++)
            Cp[(long)(lg*4+i)*HIDN + nf*16 + lr] = f2bf(o[nf][i] * lsum[i]);
}

// ---------------------------------------------------------------------------
// Fused per-head FFN1 + head reduction (3-buffer, prefetch 2, vmcnt(6)):
// S[t][i] = sum_h w_a[h]*gelu( (ctx2[t]@WcT'[i])_h + bhc[h][i] )
// bhc tile LDS-resident; merge of head h-1 between stage-issue and wait.
// ---------------------------------------------------------------------------
__global__ __launch_bounds__(512)
void gemm_heads(const bf16* __restrict__ A, const bf16* __restrict__ B,
                bf16* __restrict__ S, const float* __restrict__ bhc,
                const float* __restrict__ w_a)
{
    __shared__ __align__(16) char hlds[3*24576 + 3072];   // 3 bufs + bhc tile
    char* bhcl = hlds + 73728;

    int nwg  = gridDim.x * gridDim.y;
    int orig = blockIdx.y * gridDim.x + blockIdx.x;
    int q8 = nwg >> 3, r8 = nwg & 7;
    int xcd = orig & 7, idx = orig >> 3;
    int wg = (xcd < r8 ? xcd*(q8+1) : r8*(q8+1) + (xcd-r8)*q8) + idx;
    int bn = wg % gridDim.x, bm = wg / gridDim.x;

    int t = threadIdx.x;
    int wave = t >> 6, lane = t & 63;
    int wm = (wave >> 1) << 5;    // 0,32,64,96
    int wn = (wave & 1) << 5;     // 0,32
    int lr = lane & 15, lg = lane >> 4;
    int x7 = lr & 7;
    int gb0 = ((lg    ) ^ x7) << 4;
    int gb1 = ((4 | lg) ^ x7) << 4;

    int srow = t >> 3;
    int glog = (t & 7) ^ (srow & 7);
    const bf16* Ag0 = A + (long)(bm*128 + srow)*HIDN + glog*8;
    const bf16* Ag1 = Ag0 + (long)64*HIDN;
    const bf16* Bg0 = B + (long)(bn*64 + srow)*HIDN + glog*8;

    float wav[NH];
    #pragma unroll
    for (int h=0;h<NH;h++) wav[h] = w_a[h];

    // stage this block's bhc tile [12][64] f32 into LDS (threads 0..191);
    // this +1 outstanding load retires inside the first vmcnt(6).
    if (t < 192){
        const float* src = bhc + (t>>4)*ISZ + bn*64 + (t&15)*4;
        gload16((const bf16*)src, (bf16*)(bhcl + t*16));
    }

#define HSTAGE(buf,h) { \
    gload16(Ag0 + (h)*64, (bf16*)(hlds + (buf)*24576 + t*16)); \
    gload16(Ag1 + (h)*64, (bf16*)(hlds + (buf)*24576 + 8192 + t*16)); \
    gload16(Bg0 + (h)*64, (bf16*)(hlds + (buf)*24576 + 16384 + t*16)); }

    HSTAGE(0, 0);
    HSTAGE(1, 1);

    f32x4 acc[2][2] = {};
    f32x4 sacc[2][2] = {};

    #pragma unroll
    for (int h = 0; h < NH; ++h){
        if (h <= 9) HSTAGE((h+2)%3, h+2);
        if (h > 0){
            float bh0 = *(const float*)(bhcl + (h-1)*256 + (wn+lr)*4);
            float bh1 = *(const float*)(bhcl + (h-1)*256 + (wn+16+lr)*4);
            #pragma unroll
            for (int m=0;m<2;m++)
                #pragma unroll
                for (int n=0;n<2;n++)
                    #pragma unroll
                    for (int i=0;i<4;i++){
                        float v = acc[m][n][i] + (n ? bh1 : bh0);
                        sacc[m][n][i] = fmaf(wav[h-1], gelu_fast(v), sacc[m][n][i]);
                        acc[m][n][i] = 0.f;
                    }
        }
        if (h <= 9)       asm volatile("s_waitcnt vmcnt(6)" ::: "memory");
        else if (h == 10) asm volatile("s_waitcnt vmcnt(3)" ::: "memory");
        else              asm volatile("s_waitcnt vmcnt(0)" ::: "memory");
        FENCE; __builtin_amdgcn_s_barrier(); FENCE;

        const char* Lb = hlds + (h%3)*24576;
        short8 af[2][2], bfr[2][2];
        #pragma unroll
        for (int m=0;m<2;m++){
            const char* pr = Lb + (wm + m*16 + lr)*128;
            af[m][0] = *(const short8*)(pr + gb0);
            af[m][1] = *(const short8*)(pr + gb1);
        }
        #pragma unroll
        for (int n=0;n<2;n++){
            const char* pr = Lb + 16384 + (wn + n*16 + lr)*128;
            bfr[n][0] = *(const short8*)(pr + gb0);
            bfr[n][1] = *(const short8*)(pr + gb1);
        }
        __builtin_amdgcn_s_setprio(1);
        #pragma unroll
        for (int m=0;m<2;m++)
            #pragma unroll
            for (int n=0;n<2;n++)
                #pragma unroll
                for (int kk=0;kk<2;kk++)
                    acc[m][n] = __builtin_amdgcn_mfma_f32_16x16x32_bf16(af[m][kk], bfr[n][kk], acc[m][n], 0,0,0);
        __builtin_amdgcn_s_setprio(0);
        FENCE; __builtin_amdgcn_s_barrier(); FENCE;
    }
#undef HSTAGE

    {   // final head merge
        float bh0 = *(const float*)(bhcl + (NH-1)*256 + (wn+lr)*4);
        float bh1 = *(const float*)(bhcl + (NH-1)*256 + (wn+16+lr)*4);
        #pragma unroll
        for (int m=0;m<2;m++)
            #pragma unroll
            for (int n=0;n<2;n++)
                #pragma unroll
                for (int i=0;i<4;i++){
                    float v = acc[m][n][i] + (n ? bh1 : bh0);
                    sacc[m][n][i] = fmaf(wav[NH-1], gelu_fast(v), sacc[m][n][i]);
                }
    }

    #pragma unroll
    for (int m=0;m<2;m++)
        #pragma unroll
        for (int n=0;n<2;n++)
            #pragma unroll
            for (int i=0;i<4;i++){
                long row = (long)bm*128 + wm + m*16 + lg*4 + i;
                S[row*ISZ + bn*64 + wn + n*16 + lr] = f2bf(sacc[m][n][i]);
            }
}

// ---------------------------------------------------------------------------
// One launch: weight transposes (blocks < 6336) + elementwise prep (rest).
// ---------------------------------------------------------------------------
#define NPREP (NTOK*HIDN + HIDN*HIDN + 128*HIDN + 3*HIDN)
__global__ __launch_bounds__(256)
void prep_all(const float* __restrict__ Wq, const float* __restrict__ Wk,
              const float* __restrict__ Wv, const float* __restrict__ Wi,
              const float* __restrict__ Wout,
              bf16* __restrict__ WqkvT, bf16* __restrict__ WiT,
              bf16* __restrict__ WoutT,
              const float* __restrict__ hidden, const float* __restrict__ Wo,
              const float* __restrict__ bq, const float* __restrict__ bk,
              const float* __restrict__ bv, const float* __restrict__ bo,
              bf16* __restrict__ hbf, bf16* __restrict__ Wobf,
              float* __restrict__ bqkv, bf16* __restrict__ bo_pad)
{
    __shared__ float tile[32][33];
    int bid = blockIdx.x;
    if (bid >= 6336){
        int i = (bid-6336)*256 + threadIdx.x;
        const int n1 = NTOK*HIDN, n2 = HIDN*HIDN, n3 = 128*HIDN;
        if (i < n1) hbf[i] = f2bf(hidden[i]);
        int j = i - n1;
        if (j >= 0 && j < n2) Wobf[j] = f2bf(Wo[j]);
        int k = i - n1 - n2;
        if (k >= 0 && k < n3) bo_pad[k] = (k < NH*HIDN) ? f2bf(bo[k]) : f2bf(0.f);
        int l = i - n1 - n2 - n3;
        if (l >= 0 && l < 3*HIDN)
            bqkv[l] = (l < HIDN) ? bq[l] : (l < 2*HIDN ? bk[l-HIDN] : bv[l-2*HIDN]);
        return;
    }
    const float* src; bf16* dst; int R, C, ct, rem;
    if (bid < 1728){
        int z = bid / 576; rem = bid - z*576;
        src = (z==0) ? Wq : ((z==1) ? Wk : Wv);
        dst = WqkvT + (long)z*HIDN*HIDN;
        R = HIDN; C = HIDN; ct = 24;
    } else if (bid < 4032){
        rem = bid - 1728; src = Wi; dst = WiT; R = HIDN; C = ISZ; ct = 96;
    } else {
        rem = bid - 4032; src = Wout; dst = WoutT; R = ISZ; C = HIDN; ct = 24;
    }
    int c0 = (rem % ct)*32, r0 = (rem / ct)*32;
    int tx = threadIdx.x & 31, ty = threadIdx.x >> 5;
    #pragma unroll
    for (int i=0;i<32;i+=8) tile[ty+i][tx] = src[(long)(r0+ty+i)*C + c0+tx];
    __syncthreads();
    #pragma unroll
    for (int i=0;i<32;i+=8) dst[(long)(c0+ty+i)*R + r0+tx] = f2bf(tile[tx][ty+i]);
}

// bf16 V transpose: per z=(b,h): qkv V-slice [512 s][64 d] -> Vt[z][64 d][512 s]
__global__ __launch_bounds__(256)
void transpose_v(const bf16* __restrict__ qkv, bf16* __restrict__ Vt)
{
    __shared__ bf16 tile[32][33];
    int za = blockIdx.z; int b = za/NH, h = za - b*NH;
    const bf16* src = qkv + (long)b*SEQ*3*HIDN + 2*HIDN + h*HD;
    bf16* dst = Vt + (long)za*HD*SEQ;
    int d0 = blockIdx.x*32, s0 = blockIdx.y*32;
    int tx = threadIdx.x & 31, ty = threadIdx.x >> 5;
    #pragma unroll
    for (int i=0;i<32;i+=8) tile[ty+i][tx] = src[(long)(s0+ty+i)*(3*HIDN) + d0+tx];
    __syncthreads();
    #pragma unroll
    for (int i=0;i<32;i+=8) dst[(long)(d0+ty+i)*SEQ + s0+tx] = tile[tx][ty+i];
}

// out = LN(hidden + sum_z part[z] + swa*bout)
__global__ __launch_bounds__(256)
void add_ln(const float* __restrict__ hidden, const float* __restrict__ part,
            const float* __restrict__ bout, const float* __restrict__ w_a,
            const float* __restrict__ gamma, const float* __restrict__ beta,
            float* __restrict__ out)
{
    __shared__ float red[8];
    int row = blockIdx.x;
    int t = threadIdx.x;
    int wave = t>>6, lane = t&63;
    float swa = 0.f;
    #pragma unroll
    for (int h=0;h<NH;h++) swa += w_a[h];
    float x[3];
    float sum = 0.f;
    #pragma unroll
    for (int j=0;j<3;j++){
        int c = j*256 + t;
        long idx = (long)row*HIDN + c;
        float acc = part[idx] + part[idx + (long)NTOK*HIDN]
                  + part[idx + 2L*NTOK*HIDN] + part[idx + 3L*NTOK*HIDN];
        x[j] = hidden[idx] + acc + swa*bout[c];
        sum += x[j];
    }
    #pragma unroll
    for (int o=32;o>0;o>>=1) sum += __shfl_xor(sum,o,64);
    if (lane==0) red[wave]=sum;
    __syncthreads();
    sum = red[0]+red[1]+red[2]+red[3];
    float u = sum * (1.0f/768.0f);
    float vs = 0.f;
    #pragma unroll
    for (int j=0;j<3;j++){ float d = x[j]-u; vs += d*d; }
    #pragma unroll
    for (int o=32;o>0;o>>=1) vs += __shfl_xor(vs,o,64);
    __syncthreads();
    if (lane==0) red[4+wave]=vs;
    __syncthreads();
    vs = red[4]+red[5]+red[6]+red[7];
    float rstd = rsqrtf(vs*(1.0f/768.0f) + 1e-12f);
    #pragma unroll
    for (int j=0;j<3;j++){
        int c = j*256 + t;
        out[(long)row*HIDN + c] = gamma[c]*(x[j]-u)*rstd + beta[c];
    }
}

extern "C" void kernel_launch(void* const* d_in, const int* in_sizes, int n_in,
                              void* d_out, int out_size, void* d_ws, size_t ws_size,
                              hipStream_t stream)
{
    const float* hidden = (const float*)d_in[0];
    const float* mask   = (const float*)d_in[1];
    const float* Wq = (const float*)d_in[2];
    const float* bq = (const float*)d_in[3];
    const float* Wk = (const float*)d_in[4];
    const float* bk = (const float*)d_in[5];
    const float* Wv = (const float*)d_in[6];
    const float* bv = (const float*)d_in[7];
    const float* Wo = (const float*)d_in[8];
    const float* bo = (const float*)d_in[9];
    const float* w_kp = (const float*)d_in[10];
    const float* w_a  = (const float*)d_in[11];
    const float* Wi = (const float*)d_in[12];
    const float* bi = (const float*)d_in[13];
    const float* Wout = (const float*)d_in[14];
    const float* boutp = (const float*)d_in[15];
    const float* gamma = (const float*)d_in[16];
    const float* beta  = (const float*)d_in[17];
    float* out = (float*)d_out;

    char* w = (char*)d_ws;
    auto alloc = [&](size_t bytes)->char* {
        char* p = w; w += (bytes + 255) & ~(size_t)255; return p;
    };
    bf16*  hbf    = (bf16*) alloc((size_t)NTOK*HIDN*2);
    bf16*  WqkvT  = (bf16*) alloc((size_t)3*HIDN*HIDN*2);
    float* bqkv   = (float*)alloc((size_t)3*HIDN*4);
    bf16*  WiT    = (bf16*) alloc((size_t)ISZ*HIDN*2);
    bf16*  WoutT  = (bf16*) alloc((size_t)HIDN*ISZ*2);
    bf16*  Wobf   = (bf16*) alloc((size_t)HIDN*HIDN*2);
    bf16*  WcT    = (bf16*) alloc((size_t)ISZ*HIDN*2);
    bf16*  bo_pad = (bf16*) alloc((size_t)128*HIDN*2);
    float* bhc    = (float*)alloc((size_t)NH*ISZ*4);
    float* part   = (float*)alloc((size_t)4*NTOK*HIDN*4);   // split-K partials
    bf16*  qkv    = (bf16*) alloc((size_t)NTOK*3*HIDN*2);
    bf16*  ctx2   = (bf16*) alloc((size_t)NTOK*HIDN*2);
    bf16*  Sbuf   = (bf16*) alloc((size_t)NTOK*ISZ*2);
    bf16*  Vt     = (bf16*) alloc((size_t)NH*4*HD*SEQ*2);

    // ---- prep (transposes + elementwise, one launch) ----
    prep_all<<<6336 + (NPREP+255)/256, 256, 0, stream>>>(
        Wq, Wk, Wv, Wi, Wout, WqkvT, WiT, WoutT,
        hidden, Wo, bq, bk, bv, bo, hbf, Wobf, bqkv, bo_pad);

    // bhc[h][c] = w_kp[h]*(bo_h @ Wi)[c] + bi[c]
    gemm_bhc<<<ISZ/128, 256, 0, stream>>>(bo_pad, WiT, bhc, bi, w_kp);

    // WcT'[i][hd] = (sum_m Wi[m][i]*Wo[hd][m]) * w_kp[hd>>6]
    gemm_pipe<2><<<dim3(HIDN/64, ISZ/128, 1), 512, 0, stream>>>(
        WiT, Wobf, WcT, w_kp,
        HIDN, HIDN, HIDN, 0, 0, 0);

    // ---- QKV projection: [2048,768] @ [2304,768]^T ----
    gemm_pipe<0><<<dim3(3*HIDN/64, NTOK/128, 1), 512, 0, stream>>>(
        hbf, WqkvT, qkv, bqkv,
        HIDN, HIDN, 3*HIDN, 0, 0, 0);

    // ---- attention ----
    transpose_v<<<dim3(2,16,48), 256, 0, stream>>>(qkv, Vt);
    flash_attn<<<dim3(SEQ/32, 48), 128, 0, stream>>>(qkv, Vt, mask, ctx2);

    // ---- fused per-head FFN1 + head-reduce -> S ----
    gemm_heads<<<dim3(ISZ/64, NTOK/128), 512, 0, stream>>>(
        ctx2, WcT, Sbuf, bhc, w_a);

    // ---- FFN2': part[z] = S[:, z*768:(z+1)*768] @ WoutT[:, z*768:(z+1)*768]^T ----
    gemm_pipe<1><<<dim3(HIDN/64, NTOK/128, 4), 512, 0, stream>>>(
        Sbuf, WoutT, part, nullptr,
        ISZ, ISZ, HIDN,
        768, 768, (long)NTOK*HIDN);

    // ---- residual + partial-sum + swa*bout + LayerNorm ----
    add_ln<<<NTOK, 256, 0, stream>>>(hidden, part, boutp, w_a, gamma, beta, out);
}

// Round 12
// 132.546 us; speedup vs baseline: 1.1474x; 1.1474x over previous
//
#include <hip/hip_runtime.h>
#include <hip/hip_bf16.h>
#include <math.h>

typedef __hip_bfloat16 bf16;
typedef __attribute__((ext_vector_type(4))) float f32x4;
typedef __attribute__((ext_vector_type(8))) short short8;

#define HIDN 768
#define NTOK 2048   // B*S
#define NH 12
#define HD 64
#define ISZ 3072
#define SEQ 512

__device__ __forceinline__ bf16 f2bf(float x){ return __float2bfloat16(x); }
// tanh-approx gelu, exp2 form (log2e folded into poly; exp2f = raw v_exp_f32)
__device__ __forceinline__ float gelu_fast(float x){
    float u = x * fmaf(x*x, -0.1029432f, -2.302208f);
    float e = exp2f(u);
    return x * __builtin_amdgcn_rcpf(1.0f + e);
}

// async global->LDS, 16B per lane (LDS dest = wave base + lane*16)
__device__ __forceinline__ void gload16(const bf16* g, bf16* l){
    __builtin_amdgcn_global_load_lds(
        (const __attribute__((address_space(1))) unsigned int*)g,
        (__attribute__((address_space(3))) unsigned int*)l,
        16, 0, 0);
}

#define FENCE asm volatile("" ::: "memory")

// ---------------------------------------------------------------------------
// Pipelined GEMM core (K=768, 512 thr = 8 waves 4Mx2N, tile 128x64, BK=64,
// 2 LDS buffers, counted vmcnt(3), XOR-swizzled LDS, setprio). r10-proven.
// gemm_pipe<EPI=1>: FFN2 split-K partials (f32 store, z-batched).
// ---------------------------------------------------------------------------
template<int EPI>
__global__ __launch_bounds__(512)
void gemm_pipe(const bf16* __restrict__ A, const bf16* __restrict__ B,
               void* __restrict__ Cbase, const float* __restrict__ bias,
               int lda, int ldb, int ldc,
               long sAz, long sBz, long sCz)
{
    __shared__ __align__(16) char hlds[2*24576];
    int z = blockIdx.z;
    A += (long)z*sAz; B += (long)z*sBz;

    int nwg  = gridDim.x * gridDim.y;
    int orig = blockIdx.y * gridDim.x + blockIdx.x;
    int q8 = nwg >> 3, r8 = nwg & 7;
    int xcd = orig & 7, idx = orig >> 3;
    int wg = (xcd < r8 ? xcd*(q8+1) : r8*(q8+1) + (xcd-r8)*q8) + idx;
    int bn = wg % gridDim.x, bm = wg / gridDim.x;

    int t = threadIdx.x;
    int wave = t >> 6, lane = t & 63;
    int wm = (wave >> 1) << 5;
    int wn = (wave & 1) << 5;
    int lr = lane & 15, lg = lane >> 4;
    int x7 = lr & 7;
    int gb0 = ((lg    ) ^ x7) << 4;
    int gb1 = ((4 | lg) ^ x7) << 4;

    int srow = t >> 3;
    int glog = (t & 7) ^ (srow & 7);
    const bf16* Ag0 = A + (long)(bm*128 + srow)*lda + glog*8;
    const bf16* Ag1 = Ag0 + (long)64*lda;
    const bf16* Bg0 = B + (long)(bn*64 + srow)*ldb + glog*8;

#define PSTAGE(buf,kt) { \
    gload16(Ag0 + (kt)*64, (bf16*)(hlds + (buf)*24576 + t*16)); \
    gload16(Ag1 + (kt)*64, (bf16*)(hlds + (buf)*24576 + 8192 + t*16)); \
    gload16(Bg0 + (kt)*64, (bf16*)(hlds + (buf)*24576 + 16384 + t*16)); }

    PSTAGE(0, 0);

    f32x4 acc[2][2] = {};

    #pragma unroll
    for (int kt = 0; kt < 12; ++kt){
        if (kt < 11) PSTAGE((kt+1)&1, kt+1);
        if (kt < 11) asm volatile("s_waitcnt vmcnt(3)" ::: "memory");
        else         asm volatile("s_waitcnt vmcnt(0)" ::: "memory");
        FENCE; __builtin_amdgcn_s_barrier(); FENCE;

        const char* Lb = hlds + (kt&1)*24576;
        short8 af[2][2], bfr[2][2];
        #pragma unroll
        for (int m=0;m<2;m++){
            const char* pr = Lb + (wm + m*16 + lr)*128;
            af[m][0] = *(const short8*)(pr + gb0);
            af[m][1] = *(const short8*)(pr + gb1);
        }
        #pragma unroll
        for (int n=0;n<2;n++){
            const char* pr = Lb + 16384 + (wn + n*16 + lr)*128;
            bfr[n][0] = *(const short8*)(pr + gb0);
            bfr[n][1] = *(const short8*)(pr + gb1);
        }
        __builtin_amdgcn_s_setprio(1);
        #pragma unroll
        for (int m=0;m<2;m++)
            #pragma unroll
            for (int n=0;n<2;n++)
                #pragma unroll
                for (int kk=0;kk<2;kk++)
                    acc[m][n] = __builtin_amdgcn_mfma_f32_16x16x32_bf16(af[m][kk], bfr[n][kk], acc[m][n], 0,0,0);
        __builtin_amdgcn_s_setprio(0);
        FENCE; __builtin_amdgcn_s_barrier(); FENCE;
    }
#undef PSTAGE

    #pragma unroll
    for (int m=0;m<2;m++){
        #pragma unroll
        for (int n=0;n<2;n++){
            int col = bn*64 + wn + n*16 + lr;
            #pragma unroll
            for (int i=0;i<4;i++){
                long row = (long)bm*128 + wm + m*16 + lg*4 + i;
                ((float*)Cbase + (long)z*sCz)[row*ldc+col] = acc[m][n][i];
            }
        }
    }
}

// ---------------------------------------------------------------------------
// Fused pre-GEMM: one launch, three segments (all K=768, same pipeline).
//   [0,48):    bhc  = bo_pad[128,768] @ WiT^T   -> f32 [12][3072], row<12
//   [48,336):  WcT  = WiT[3072,768] @ Wobf^T    -> bf16, * w_kp[col>>6]
//   [336,912): qkv  = hbf[2048,768] @ WqkvT^T   -> bf16, + bqkv[col]
// ---------------------------------------------------------------------------
__global__ __launch_bounds__(512)
void gemm_pre(const bf16* __restrict__ WiT, const bf16* __restrict__ Wobf,
              const bf16* __restrict__ bo_pad, const bf16* __restrict__ hbf,
              const bf16* __restrict__ WqkvT,
              bf16* __restrict__ WcT, float* __restrict__ bhc,
              bf16* __restrict__ qkv,
              const float* __restrict__ w_kp, const float* __restrict__ bi,
              const float* __restrict__ bqkv)
{
    __shared__ __align__(16) char hlds[2*24576];
    int bid = blockIdx.x;
    int mode, local, gx, nwg, ldc;
    const bf16 *A, *B;
    if (bid < 48){        mode=0; local=bid;     gx=48; nwg=48;  A=bo_pad; B=WiT;   ldc=ISZ; }
    else if (bid < 336){  mode=1; local=bid-48;  gx=12; nwg=288; A=WiT;    B=Wobf;  ldc=HIDN; }
    else {                mode=2; local=bid-336; gx=36; nwg=576; A=hbf;    B=WqkvT; ldc=3*HIDN; }

    int cpx = nwg >> 3;
    int wg = (local & 7)*cpx + (local >> 3);   // nwg%8==0 for all segments
    int bn = wg % gx, bm = wg / gx;

    int t = threadIdx.x;
    int wave = t >> 6, lane = t & 63;
    int wm = (wave >> 1) << 5;
    int wn = (wave & 1) << 5;
    int lr = lane & 15, lg = lane >> 4;
    int x7 = lr & 7;
    int gb0 = ((lg    ) ^ x7) << 4;
    int gb1 = ((4 | lg) ^ x7) << 4;

    int srow = t >> 3;
    int glog = (t & 7) ^ (srow & 7);
    const bf16* Ag0 = A + (long)(bm*128 + srow)*HIDN + glog*8;
    const bf16* Ag1 = Ag0 + (long)64*HIDN;
    const bf16* Bg0 = B + (long)(bn*64 + srow)*HIDN + glog*8;

#define PSTAGE(buf,kt) { \
    gload16(Ag0 + (kt)*64, (bf16*)(hlds + (buf)*24576 + t*16)); \
    gload16(Ag1 + (kt)*64, (bf16*)(hlds + (buf)*24576 + 8192 + t*16)); \
    gload16(Bg0 + (kt)*64, (bf16*)(hlds + (buf)*24576 + 16384 + t*16)); }

    PSTAGE(0, 0);

    f32x4 acc[2][2] = {};

    #pragma unroll
    for (int kt = 0; kt < 12; ++kt){
        if (kt < 11) PSTAGE((kt+1)&1, kt+1);
        if (kt < 11) asm volatile("s_waitcnt vmcnt(3)" ::: "memory");
        else         asm volatile("s_waitcnt vmcnt(0)" ::: "memory");
        FENCE; __builtin_amdgcn_s_barrier(); FENCE;

        const char* Lb = hlds + (kt&1)*24576;
        short8 af[2][2], bfr[2][2];
        #pragma unroll
        for (int m=0;m<2;m++){
            const char* pr = Lb + (wm + m*16 + lr)*128;
            af[m][0] = *(const short8*)(pr + gb0);
            af[m][1] = *(const short8*)(pr + gb1);
        }
        #pragma unroll
        for (int n=0;n<2;n++){
            const char* pr = Lb + 16384 + (wn + n*16 + lr)*128;
            bfr[n][0] = *(const short8*)(pr + gb0);
            bfr[n][1] = *(const short8*)(pr + gb1);
        }
        __builtin_amdgcn_s_setprio(1);
        #pragma unroll
        for (int m=0;m<2;m++)
            #pragma unroll
            for (int n=0;n<2;n++)
                #pragma unroll
                for (int kk=0;kk<2;kk++)
                    acc[m][n] = __builtin_amdgcn_mfma_f32_16x16x32_bf16(af[m][kk], bfr[n][kk], acc[m][n], 0,0,0);
        __builtin_amdgcn_s_setprio(0);
        FENCE; __builtin_amdgcn_s_barrier(); FENCE;
    }
#undef PSTAGE

    #pragma unroll
    for (int m=0;m<2;m++){
        #pragma unroll
        for (int n=0;n<2;n++){
            int col = bn*64 + wn + n*16 + lr;
            #pragma unroll
            for (int i=0;i<4;i++){
                long row = (long)bm*128 + wm + m*16 + lg*4 + i;
                float v = acc[m][n][i];
                if (mode == 0){
                    if (row < NH) bhc[row*ISZ+col] = fmaf(w_kp[row], v, bi[col]);
                } else if (mode == 1){
                    WcT[row*HIDN+col] = f2bf(v * w_kp[col>>6]);
                } else {
                    qkv[row*(3*HIDN)+col] = f2bf(v + bqkv[col]);
                }
            }
        }
    }
}

// ---------------------------------------------------------------------------
// Fused flash attention (max-free single pass; scores provably small).
// 128 threads = 2 waves; wave owns 16 q-rows. Zero barriers (per-wave LDS).
// ---------------------------------------------------------------------------
__global__ __launch_bounds__(128)
void flash_attn(const bf16* __restrict__ qkv, const bf16* __restrict__ Vt,
                const float* __restrict__ mask, bf16* __restrict__ ctx2)
{
    __shared__ __align__(16) char p_lds[4096];
    int z = blockIdx.y;
    int b = z / NH, h = z - b*NH;
    int t = threadIdx.x;
    int wave = t >> 6, lane = t & 63;
    int q0 = blockIdx.x*32 + wave*16;
    int lr = lane & 15, lg = lane >> 4;
    int x7 = lr & 7;
    int gb0 = ((lg    ) ^ x7) << 4;
    int gb1 = ((4 | lg) ^ x7) << 4;

    const bf16* Qp = qkv + (long)(b*SEQ + q0 + lr)*(3*HIDN) + h*HD + lg*8;
    short8 aq0 = *(const short8*)(Qp);
    short8 aq1 = *(const short8*)(Qp + 32);

    const bf16* Kb = qkv + (long)b*SEQ*(3*HIDN) + HIDN + h*HD + lg*8;
    const bf16* Vb = Vt + (long)z*HD*SEQ;
    const float* mb = mask + b*SEQ;
    char* pw = p_lds + wave*2048;

    f32x4 o[4] = {};
    float lsum[4] = {0.f,0.f,0.f,0.f};

    for (int kt = 0; kt < 8; ++kt){
        int kbase = kt*64;
        short8 bk0[4], bk1[4];
        #pragma unroll
        for (int nf=0;nf<4;nf++){
            const bf16* kp = Kb + (long)(kbase + nf*16 + lr)*(3*HIDN);
            bk0[nf] = *(const short8*)(kp);
            bk1[nf] = *(const short8*)(kp + 32);
        }
        f32x4 s[4] = {};
        #pragma unroll
        for (int nf=0;nf<4;nf++){
            s[nf] = __builtin_amdgcn_mfma_f32_16x16x32_bf16(aq0, bk0[nf], s[nf], 0,0,0);
            s[nf] = __builtin_amdgcn_mfma_f32_16x16x32_bf16(aq1, bk1[nf], s[nf], 0,0,0);
        }
        short8 bv0[4], bv1[4];
        #pragma unroll
        for (int nf=0;nf<4;nf++){
            const bf16* vp = Vb + (long)(nf*16 + lr)*SEQ + kbase + lg*8;
            bv0[nf] = *(const short8*)(vp);
            bv1[nf] = *(const short8*)(vp + 32);
        }
        #pragma unroll
        for (int nf=0;nf<4;nf++){
            float mkl = mb[kbase + nf*16 + lr] * 1.442695041f;
            int gk = nf*2 + (lr>>3);
            #pragma unroll
            for (int i=0;i<4;i++){
                int q = lg*4 + i;
                float e = exp2f(fmaf(s[nf][i], 0.18033688f, mkl));
                lsum[i] += e;
                *(bf16*)(pw + q*128 + ((gk ^ (q&7))<<4) + (lr&7)*2) = f2bf(e);
            }
        }
        short8 ap0 = *(const short8*)(pw + lr*128 + gb0);
        short8 ap1 = *(const short8*)(pw + lr*128 + gb1);
        #pragma unroll
        for (int nf=0;nf<4;nf++){
            o[nf] = __builtin_amdgcn_mfma_f32_16x16x32_bf16(ap0, bv0[nf], o[nf], 0,0,0);
            o[nf] = __builtin_amdgcn_mfma_f32_16x16x32_bf16(ap1, bv1[nf], o[nf], 0,0,0);
        }
    }
    #pragma unroll
    for (int i=0;i<4;i++){
        float v = lsum[i];
        v += __shfl_xor(v, 1, 64);
        v += __shfl_xor(v, 2, 64);
        v += __shfl_xor(v, 4, 64);
        v += __shfl_xor(v, 8, 64);
        lsum[i] = __builtin_amdgcn_rcpf(v);
    }
    bf16* Cp = ctx2 + (long)(b*SEQ + q0)*HIDN + h*HD;
    #pragma unroll
    for (int nf=0;nf<4;nf++)
        #pragma unroll
        for (int i=0;i<4;i++)
            Cp[(long)(lg*4+i)*HIDN + nf*16 + lr] = f2bf(o[nf][i] * lsum[i]);
}

// ---------------------------------------------------------------------------
// Fused per-head FFN1 + head reduction (2-buffer vmcnt(3), r10 structure,
// + 2D-chunked XCD swizzle: each XCD owns 8bm x 12bn -> A+B fit its 4MB L2,
// + fresh accumulator per head (MFMA with C=0, no explicit zeroing)).
// S[t][i] = sum_h w_a[h]*gelu( (ctx2[t]@WcT'[i])_h + bhc[h][i] )
// ---------------------------------------------------------------------------
__global__ __launch_bounds__(512)
void gemm_heads(const bf16* __restrict__ A, const bf16* __restrict__ B,
                bf16* __restrict__ S, const float* __restrict__ bhc,
                const float* __restrict__ w_a)
{
    __shared__ __align__(16) char hlds[2*24576 + 3072];
    char* bhcl = hlds + 49152;

    // 2D-chunked bijective XCD swizzle: grid (48,16)=768, xcd chunk 8bm x 12bn
    int orig = blockIdx.y*48 + blockIdx.x;
    int xcd = orig & 7, idx = orig >> 3;           // idx in [0,96)
    int bm = ((xcd >> 2) << 3) + idx/12;           // [0,16)
    int bn = (xcd & 3)*12 + idx%12;                // [0,48)

    int t = threadIdx.x;
    int wave = t >> 6, lane = t & 63;
    int wm = (wave >> 1) << 5;
    int wn = (wave & 1) << 5;
    int lr = lane & 15, lg = lane >> 4;
    int x7 = lr & 7;
    int gb0 = ((lg    ) ^ x7) << 4;
    int gb1 = ((4 | lg) ^ x7) << 4;

    int srow = t >> 3;
    int glog = (t & 7) ^ (srow & 7);
    const bf16* Ag0 = A + (long)(bm*128 + srow)*HIDN + glog*8;
    const bf16* Ag1 = Ag0 + (long)64*HIDN;
    const bf16* Bg0 = B + (long)(bn*64 + srow)*HIDN + glog*8;

    float wav[NH];
    #pragma unroll
    for (int h=0;h<NH;h++) wav[h] = w_a[h];

    if (t < 192){
        const float* src = bhc + (t>>4)*ISZ + bn*64 + (t&15)*4;
        gload16((const bf16*)src, (bf16*)(bhcl + t*16));
    }

#define HSTAGE(buf,h) { \
    gload16(Ag0 + (h)*64, (bf16*)(hlds + (buf)*24576 + t*16)); \
    gload16(Ag1 + (h)*64, (bf16*)(hlds + (buf)*24576 + 8192 + t*16)); \
    gload16(Bg0 + (h)*64, (bf16*)(hlds + (buf)*24576 + 16384 + t*16)); }

    HSTAGE(0, 0);

    const f32x4 zz = {};
    f32x4 acc[2][2] = {};
    f32x4 sacc[2][2] = {};

    #pragma unroll
    for (int h = 0; h < NH; ++h){
        if (h < NH-1) HSTAGE((h+1)&1, h+1);
        if (h > 0){
            float bh0 = *(const float*)(bhcl + (h-1)*256 + (wn+lr)*4);
            float bh1 = *(const float*)(bhcl + (h-1)*256 + (wn+16+lr)*4);
            #pragma unroll
            for (int m=0;m<2;m++)
                #pragma unroll
                for (int n=0;n<2;n++)
                    #pragma unroll
                    for (int i=0;i<4;i++){
                        float v = acc[m][n][i] + (n ? bh1 : bh0);
                        sacc[m][n][i] = fmaf(wav[h-1], gelu_fast(v), sacc[m][n][i]);
                    }
        }
        if (h < NH-1) asm volatile("s_waitcnt vmcnt(3)" ::: "memory");
        else          asm volatile("s_waitcnt vmcnt(0)" ::: "memory");
        FENCE; __builtin_amdgcn_s_barrier(); FENCE;

        const char* Lb = hlds + (h&1)*24576;
        short8 af[2][2], bfr[2][2];
        #pragma unroll
        for (int m=0;m<2;m++){
            const char* pr = Lb + (wm + m*16 + lr)*128;
            af[m][0] = *(const short8*)(pr + gb0);
            af[m][1] = *(const short8*)(pr + gb1);
        }
        #pragma unroll
        for (int n=0;n<2;n++){
            const char* pr = Lb + 16384 + (wn + n*16 + lr)*128;
            bfr[n][0] = *(const short8*)(pr + gb0);
            bfr[n][1] = *(const short8*)(pr + gb1);
        }
        __builtin_amdgcn_s_setprio(1);
        #pragma unroll
        for (int m=0;m<2;m++)
            #pragma unroll
            for (int n=0;n<2;n++)
                acc[m][n] = __builtin_amdgcn_mfma_f32_16x16x32_bf16(af[m][1], bfr[n][1],
                    __builtin_amdgcn_mfma_f32_16x16x32_bf16(af[m][0], bfr[n][0], zz, 0,0,0), 0,0,0);
        __builtin_amdgcn_s_setprio(0);
        FENCE; __builtin_amdgcn_s_barrier(); FENCE;
    }
#undef HSTAGE

    {   // final head merge
        float bh0 = *(const float*)(bhcl + (NH-1)*256 + (wn+lr)*4);
        float bh1 = *(const float*)(bhcl + (NH-1)*256 + (wn+16+lr)*4);
        #pragma unroll
        for (int m=0;m<2;m++)
            #pragma unroll
            for (int n=0;n<2;n++)
                #pragma unroll
                for (int i=0;i<4;i++){
                    float v = acc[m][n][i] + (n ? bh1 : bh0);
                    sacc[m][n][i] = fmaf(wav[NH-1], gelu_fast(v), sacc[m][n][i]);
                }
    }

    #pragma unroll
    for (int m=0;m<2;m++)
        #pragma unroll
        for (int n=0;n<2;n++)
            #pragma unroll
            for (int i=0;i<4;i++){
                long row = (long)bm*128 + wm + m*16 + lg*4 + i;
                S[row*ISZ + bn*64 + wn + n*16 + lr] = f2bf(sacc[m][n][i]);
            }
}

// ---------------------------------------------------------------------------
// One launch: weight transposes (blocks < 6336) + elementwise prep (rest).
// ---------------------------------------------------------------------------
#define NPREP (NTOK*HIDN + HIDN*HIDN + 128*HIDN + 3*HIDN)
__global__ __launch_bounds__(256)
void prep_all(const float* __restrict__ Wq, const float* __restrict__ Wk,
              const float* __restrict__ Wv, const float* __restrict__ Wi,
              const float* __restrict__ Wout,
              bf16* __restrict__ WqkvT, bf16* __restrict__ WiT,
              bf16* __restrict__ WoutT,
              const float* __restrict__ hidden, const float* __restrict__ Wo,
              const float* __restrict__ bq, const float* __restrict__ bk,
              const float* __restrict__ bv, const float* __restrict__ bo,
              bf16* __restrict__ hbf, bf16* __restrict__ Wobf,
              float* __restrict__ bqkv, bf16* __restrict__ bo_pad)
{
    __shared__ float tile[32][33];
    int bid = blockIdx.x;
    if (bid >= 6336){
        int i = (bid-6336)*256 + threadIdx.x;
        const int n1 = NTOK*HIDN, n2 = HIDN*HIDN, n3 = 128*HIDN;
        if (i < n1) hbf[i] = f2bf(hidden[i]);
        int j = i - n1;
        if (j >= 0 && j < n2) Wobf[j] = f2bf(Wo[j]);
        int k = i - n1 - n2;
        if (k >= 0 && k < n3) bo_pad[k] = (k < NH*HIDN) ? f2bf(bo[k]) : f2bf(0.f);
        int l = i - n1 - n2 - n3;
        if (l >= 0 && l < 3*HIDN)
            bqkv[l] = (l < HIDN) ? bq[l] : (l < 2*HIDN ? bk[l-HIDN] : bv[l-2*HIDN]);
        return;
    }
    const float* src; bf16* dst; int R, C, ct, rem;
    if (bid < 1728){
        int z = bid / 576; rem = bid - z*576;
        src = (z==0) ? Wq : ((z==1) ? Wk : Wv);
        dst = WqkvT + (long)z*HIDN*HIDN;
        R = HIDN; C = HIDN; ct = 24;
    } else if (bid < 4032){
        rem = bid - 1728; src = Wi; dst = WiT; R = HIDN; C = ISZ; ct = 96;
    } else {
        rem = bid - 4032; src = Wout; dst = WoutT; R = ISZ; C = HIDN; ct = 24;
    }
    int c0 = (rem % ct)*32, r0 = (rem / ct)*32;
    int tx = threadIdx.x & 31, ty = threadIdx.x >> 5;
    #pragma unroll
    for (int i=0;i<32;i+=8) tile[ty+i][tx] = src[(long)(r0+ty+i)*C + c0+tx];
    __syncthreads();
    #pragma unroll
    for (int i=0;i<32;i+=8) dst[(long)(c0+ty+i)*R + r0+tx] = f2bf(tile[tx][ty+i]);
}

// bf16 V transpose: per z=(b,h): qkv V-slice [512 s][64 d] -> Vt[z][64 d][512 s]
__global__ __launch_bounds__(256)
void transpose_v(const bf16* __restrict__ qkv, bf16* __restrict__ Vt)
{
    __shared__ bf16 tile[32][33];
    int za = blockIdx.z; int b = za/NH, h = za - b*NH;
    const bf16* src = qkv + (long)b*SEQ*3*HIDN + 2*HIDN + h*HD;
    bf16* dst = Vt + (long)za*HD*SEQ;
    int d0 = blockIdx.x*32, s0 = blockIdx.y*32;
    int tx = threadIdx.x & 31, ty = threadIdx.x >> 5;
    #pragma unroll
    for (int i=0;i<32;i+=8) tile[ty+i][tx] = src[(long)(s0+ty+i)*(3*HIDN) + d0+tx];
    __syncthreads();
    #pragma unroll
    for (int i=0;i<32;i+=8) dst[(long)(d0+ty+i)*SEQ + s0+tx] = tile[tx][ty+i];
}

// out = LN(hidden + sum_z part[z] + swa*bout)
__global__ __launch_bounds__(256)
void add_ln(const float* __restrict__ hidden, const float* __restrict__ part,
            const float* __restrict__ bout, const float* __restrict__ w_a,
            const float* __restrict__ gamma, const float* __restrict__ beta,
            float* __restrict__ out)
{
    __shared__ float red[8];
    int row = blockIdx.x;
    int t = threadIdx.x;
    int wave = t>>6, lane = t&63;
    float swa = 0.f;
    #pragma unroll
    for (int h=0;h<NH;h++) swa += w_a[h];
    float x[3];
    float sum = 0.f;
    #pragma unroll
    for (int j=0;j<3;j++){
        int c = j*256 + t;
        long idx = (long)row*HIDN + c;
        float acc = part[idx] + part[idx + (long)NTOK*HIDN]
                  + part[idx + 2L*NTOK*HIDN] + part[idx + 3L*NTOK*HIDN];
        x[j] = hidden[idx] + acc + swa*bout[c];
        sum += x[j];
    }
    #pragma unroll
    for (int o=32;o>0;o>>=1) sum += __shfl_xor(sum,o,64);
    if (lane==0) red[wave]=sum;
    __syncthreads();
    sum = red[0]+red[1]+red[2]+red[3];
    float u = sum * (1.0f/768.0f);
    float vs = 0.f;
    #pragma unroll
    for (int j=0;j<3;j++){ float d = x[j]-u; vs += d*d; }
    #pragma unroll
    for (int o=32;o>0;o>>=1) vs += __shfl_xor(vs,o,64);
    __syncthreads();
    if (lane==0) red[4+wave]=vs;
    __syncthreads();
    vs = red[4]+red[5]+red[6]+red[7];
    float rstd = rsqrtf(vs*(1.0f/768.0f) + 1e-12f);
    #pragma unroll
    for (int j=0;j<3;j++){
        int c = j*256 + t;
        out[(long)row*HIDN + c] = gamma[c]*(x[j]-u)*rstd + beta[c];
    }
}

extern "C" void kernel_launch(void* const* d_in, const int* in_sizes, int n_in,
                              void* d_out, int out_size, void* d_ws, size_t ws_size,
                              hipStream_t stream)
{
    const float* hidden = (const float*)d_in[0];
    const float* mask   = (const float*)d_in[1];
    const float* Wq = (const float*)d_in[2];
    const float* bq = (const float*)d_in[3];
    const float* Wk = (const float*)d_in[4];
    const float* bk = (const float*)d_in[5];
    const float* Wv = (const float*)d_in[6];
    const float* bv = (const float*)d_in[7];
    const float* Wo = (const float*)d_in[8];
    const float* bo = (const float*)d_in[9];
    const float* w_kp = (const float*)d_in[10];
    const float* w_a  = (const float*)d_in[11];
    const float* Wi = (const float*)d_in[12];
    const float* bi = (const float*)d_in[13];
    const float* Wout = (const float*)d_in[14];
    const float* boutp = (const float*)d_in[15];
    const float* gamma = (const float*)d_in[16];
    const float* beta  = (const float*)d_in[17];
    float* out = (float*)d_out;

    char* w = (char*)d_ws;
    auto alloc = [&](size_t bytes)->char* {
        char* p = w; w += (bytes + 255) & ~(size_t)255; return p;
    };
    bf16*  hbf    = (bf16*) alloc((size_t)NTOK*HIDN*2);
    bf16*  WqkvT  = (bf16*) alloc((size_t)3*HIDN*HIDN*2);
    float* bqkv   = (float*)alloc((size_t)3*HIDN*4);
    bf16*  WiT    = (bf16*) alloc((size_t)ISZ*HIDN*2);
    bf16*  WoutT  = (bf16*) alloc((size_t)HIDN*ISZ*2);
    bf16*  Wobf   = (bf16*) alloc((size_t)HIDN*HIDN*2);
    bf16*  WcT    = (bf16*) alloc((size_t)ISZ*HIDN*2);
    bf16*  bo_pad = (bf16*) alloc((size_t)128*HIDN*2);
    float* bhc    = (float*)alloc((size_t)NH*ISZ*4);
    float* part   = (float*)alloc((size_t)4*NTOK*HIDN*4);
    bf16*  qkv    = (bf16*) alloc((size_t)NTOK*3*HIDN*2);
    bf16*  ctx2   = (bf16*) alloc((size_t)NTOK*HIDN*2);
    bf16*  Sbuf   = (bf16*) alloc((size_t)NTOK*ISZ*2);
    bf16*  Vt     = (bf16*) alloc((size_t)NH*4*HD*SEQ*2);

    // ---- prep (transposes + elementwise, one launch) ----
    prep_all<<<6336 + (NPREP+255)/256, 256, 0, stream>>>(
        Wq, Wk, Wv, Wi, Wout, WqkvT, WiT, WoutT,
        hidden, Wo, bq, bk, bv, bo, hbf, Wobf, bqkv, bo_pad);

    // ---- fused pre-GEMMs: bhc + WcT + QKV in one launch ----
    gemm_pre<<<912, 512, 0, stream>>>(
        WiT, Wobf, bo_pad, hbf, WqkvT,
        WcT, bhc, qkv, w_kp, bi, bqkv);

    // ---- attention ----
    transpose_v<<<dim3(2,16,48), 256, 0, stream>>>(qkv, Vt);
    flash_attn<<<dim3(SEQ/32, 48), 128, 0, stream>>>(qkv, Vt, mask, ctx2);

    // ---- fused per-head FFN1 + head-reduce -> S ----
    gemm_heads<<<dim3(ISZ/64, NTOK/128), 512, 0, stream>>>(
        ctx2, WcT, Sbuf, bhc, w_a);

    // ---- FFN2': part[z] = S[:, z*768:(z+1)*768] @ WoutT[:, z*768:(z+1)*768]^T ----
    gemm_pipe<1><<<dim3(HIDN/64, NTOK/128, 4), 512, 0, stream>>>(
        Sbuf, WoutT, part, nullptr,
        ISZ, ISZ, HIDN,
        768, 768, (long)NTOK*HIDN);

    // ---- residual + partial-sum + swa*bout + LayerNorm ----
    add_ln<<<NTOK, 256, 0, stream>>>(hidden, part, boutp, w_a, gamma, beta, out);
}